// Round 5
// baseline (106.317 us; speedup 1.0000x reference)
//
#include <hip/hip_runtime.h>
#include <hip/hip_bf16.h>

#define NUM_CLASSES 200
#define NF 128
#define NP 2000
#define NP_PAD 2048
#define HW 196
#define MPAD 208        // 13 * 16
#define NB 64
#define EPSV 1e-4f
#define LDS_ROW 136     // 128 shorts + 8 pad (272 B)

typedef __attribute__((ext_vector_type(8))) short short8;   // 8 bf16 = 4 VGPR
typedef __attribute__((ext_vector_type(4))) float f32x4;

static __device__ __forceinline__ unsigned short f2bf(float x) {
    __hip_bfloat16 h = __float2bfloat16(x);
    return __builtin_bit_cast(unsigned short, h);
}

// ---- kernel 0 (merged prep): grid 832 + 64 + 128 + 8 = 1032 blocks ----------
__global__ __launch_bounds__(256) void kprep(const float* __restrict__ f,
                                             const float* __restrict__ protos,
                                             float* __restrict__ xsq,
                                             float* __restrict__ psq,
                                             unsigned short* __restrict__ pT,
                                             unsigned short* __restrict__ fT) {
    __shared__ float tile[NF][21];
    const int b = blockIdx.x, t = threadIdx.x;
    if (b < 832) {
        const int hw0 = (b % 13) * 16;
        const int n   = b / 13;
        {
            int kb  = t >> 2;
            int hwl = (t & 3) * 4;
            int hw  = hw0 + hwl;
            bool valid = hw < HW;
            #pragma unroll
            for (int i = 0; i < 2; ++i) {
                int k = kb + 64 * i;
                float4 v = valid ? *(const float4*)(f + ((size_t)n * NF + k) * HW + hw)
                                 : make_float4(0.f, 0.f, 0.f, 0.f);
                tile[k][hwl + 0] = v.x;
                tile[k][hwl + 1] = v.y;
                tile[k][hwl + 2] = v.z;
                tile[k][hwl + 3] = v.w;
            }
        }
        __syncthreads();
        {
            int hwl = t >> 4;
            int kc  = (t & 15) * 8;
            unsigned short u[8];
            #pragma unroll
            for (int j = 0; j < 8; ++j) u[j] = f2bf(tile[kc + j][hwl]);
            size_t row = (size_t)n * MPAD + hw0 + hwl;
            *(uint4*)(fT + row * NF + kc) = *(uint4*)u;
        }
    } else if (b < 896) {
        int n = b - 832;
        if (t < HW) {
            const float* fn = f + (size_t)n * NF * HW;
            float s = 0.f;
            #pragma unroll 4
            for (int d = 0; d < NF; ++d) {
                float v = fn[d * HW + t];
                s += v * v;
            }
            xsq[n * HW + t] = s;
        }
    } else if (b < 1024) {
        int idx = (b - 896) * 256 + t;
        int p  = idx >> 4;
        int kc = (idx & 15) * 8;
        unsigned short u[8];
        if (p < NP) {
            const float* src = protos + (size_t)p * NF + kc;
            float4 v0 = *(const float4*)(src);
            float4 v1 = *(const float4*)(src + 4);
            u[0] = f2bf(v0.x); u[1] = f2bf(v0.y); u[2] = f2bf(v0.z); u[3] = f2bf(v0.w);
            u[4] = f2bf(v1.x); u[5] = f2bf(v1.y); u[6] = f2bf(v1.z); u[7] = f2bf(v1.w);
        } else {
            #pragma unroll
            for (int j = 0; j < 8; ++j) u[j] = 0;
        }
        *(uint4*)(pT + (size_t)p * NF + kc) = *(uint4*)u;
    } else {
        int p = (b - 1024) * 256 + t;
        float s = 0.f;
        if (p < NP) {
            const float* r = protos + (size_t)p * NF;
            #pragma unroll
            for (int d = 0; d < NF; d += 4) {
                float4 v = *(const float4*)(r + d);
                s += v.x * v.x + v.y * v.y + v.z * v.z + v.w * v.w;
            }
        }
        psq[p] = s;
    }
}

// ---- kernel 1: MFMA distance + min + fused sim -------------------------------
// grid (64 n, 4 p-tiles of 512). Block 4 waves; wave -> 128 protos (8 groups).
// fT[n] staged once in LDS per block; xsq staged in LDS (keeps mt-loop rolled).
__global__ __launch_bounds__(256) void kdist(const unsigned short* __restrict__ pT,
                                             const unsigned short* __restrict__ fT,
                                             const float* __restrict__ xsq,
                                             const float* __restrict__ psq,
                                             float* __restrict__ min_out,
                                             float* __restrict__ sim_out) {
    __shared__ unsigned short sf[MPAD * LDS_ROW];   // 56,576 B
    __shared__ float sxsq[MPAD];                    // 832 B

    const int n    = blockIdx.x;
    const int pt   = blockIdx.y;
    const int t    = threadIdx.x;
    const int wave = t >> 6;
    const int lane = t & 63;
    const int row  = lane & 15;
    const int quad = lane >> 4;
    const int pb   = pt * 512 + wave * 128;

    // A frags: 8 proto-groups x 4 k-chunks (32 global dwordx4 loads, issued early)
    short8 A[8][4];
    {
        const unsigned short* ap = pT + (size_t)(pb + row) * NF + quad * 8;
        #pragma unroll
        for (int g = 0; g < 8; ++g)
            #pragma unroll
            for (int kk = 0; kk < 4; ++kk)
                A[g][kk] = *(const short8*)(ap + (size_t)g * 16 * NF + kk * 32);
    }

    // stage xsq -> LDS (invalid hw get +inf so they can't win the min)
    if (t < MPAD) sxsq[t] = (t < HW) ? xsq[n * HW + t] : 3.0e38f;

    // stage fT[n] (208x128 bf16) into LDS: 13 independent wide loads in flight
    {
        const unsigned short* fb = fT + (size_t)n * MPAD * NF;
        const int srow = t >> 4;           // 0..15
        const int scol = (t & 15) * 8;     // shorts
        uint4 tmp[13];
        #pragma unroll
        for (int i = 0; i < 13; ++i)
            tmp[i] = *(const uint4*)(fb + (size_t)(i * 16 + srow) * NF + scol);
        #pragma unroll
        for (int i = 0; i < 13; ++i)
            *(uint4*)(sf + (i * 16 + srow) * LDS_ROW + scol) = tmp[i];
    }
    __syncthreads();

    float runmin[8][4];
    #pragma unroll
    for (int g = 0; g < 8; ++g)
        #pragma unroll
        for (int r = 0; r < 4; ++r) runmin[g][r] = 3.0e38f;

    for (int mt = 0; mt < 13; ++mt) {
        const unsigned short* bp = sf + (mt * 16 + row) * LDS_ROW + quad * 8;
        short8 bfrag[4];
        #pragma unroll
        for (int kk = 0; kk < 4; ++kk)
            bfrag[kk] = *(const short8*)(bp + kk * 32);
        float xv = sxsq[mt * 16 + row];

        #pragma unroll
        for (int g = 0; g < 8; ++g) {
            f32x4 acc = {0.f, 0.f, 0.f, 0.f};
            acc = __builtin_amdgcn_mfma_f32_16x16x32_bf16(A[g][0], bfrag[0], acc, 0, 0, 0);
            acc = __builtin_amdgcn_mfma_f32_16x16x32_bf16(A[g][1], bfrag[1], acc, 0, 0, 0);
            acc = __builtin_amdgcn_mfma_f32_16x16x32_bf16(A[g][2], bfrag[2], acc, 0, 0, 0);
            acc = __builtin_amdgcn_mfma_f32_16x16x32_bf16(A[g][3], bfrag[3], acc, 0, 0, 0);
            #pragma unroll
            for (int r = 0; r < 4; ++r)
                runmin[g][r] = fminf(runmin[g][r], xv - 2.f * acc[r]);
        }
    }

    // min across the 16 D-columns, then epilogue
    #pragma unroll
    for (int g = 0; g < 8; ++g) {
        #pragma unroll
        for (int off = 1; off < 16; off <<= 1)
            #pragma unroll
            for (int r = 0; r < 4; ++r)
                runmin[g][r] = fminf(runmin[g][r], __shfl_xor(runmin[g][r], off, 64));
        if (row == 0) {
            #pragma unroll
            for (int r = 0; r < 4; ++r) {
                int p = pb + g * 16 + quad * 4 + r;
                if (p < NP) {
                    float m = fmaxf(runmin[g][r] + psq[p], 0.f);
                    min_out[(size_t)n * NP + p] = m;
                    sim_out[(size_t)n * NP + p] = logf((m + 1.f) / (m + EPSV));
                }
            }
        }
    }
}

// ---- kernel 2: logits, n-tiled with sim in LDS -------------------------------
// grid (8 n-tiles, 25 c-tiles); block covers 8 n x 8 classes (2 per wave).
__global__ __launch_bounds__(256) void klogits(const float* __restrict__ sim,
                                               const float* __restrict__ W,
                                               float* __restrict__ logits) {
    __shared__ float ssim[8][NP];      // 62.5 KB
    const int nt = blockIdx.x;
    const int cb = blockIdx.y;
    const int t  = threadIdx.x;

    // load 8 sim rows (coalesced float4)
    #pragma unroll
    for (int ni = 0; ni < 8; ++ni) {
        const float4* src = (const float4*)(sim + (size_t)(nt * 8 + ni) * NP);
        float4* dst = (float4*)ssim[ni];
        for (int j = t; j < NP / 4; j += 256) dst[j] = src[j];
    }
    __syncthreads();

    const int wave = t >> 6;
    const int lane = t & 63;
    const int c0   = cb * 8 + wave * 2;

    const float4* w0 = (const float4*)(W + (size_t)c0 * NP);
    const float4* w1 = (const float4*)(W + (size_t)(c0 + 1) * NP);

    float acc[2][8];
    #pragma unroll
    for (int cc = 0; cc < 2; ++cc)
        #pragma unroll
        for (int ni = 0; ni < 8; ++ni) acc[cc][ni] = 0.f;

    #pragma unroll
    for (int it = 0; it < 8; ++it) {
        int idx = it * 64 + lane;
        if (idx < NP / 4) {
            float4 a = w0[idx];
            float4 b = w1[idx];
            #pragma unroll
            for (int ni = 0; ni < 8; ++ni) {
                float4 s = ((const float4*)ssim[ni])[idx];
                acc[0][ni] += a.x * s.x + a.y * s.y + a.z * s.z + a.w * s.w;
                acc[1][ni] += b.x * s.x + b.y * s.y + b.z * s.z + b.w * s.w;
            }
        }
    }

    #pragma unroll
    for (int cc = 0; cc < 2; ++cc)
        #pragma unroll
        for (int ni = 0; ni < 8; ++ni) {
            float v = acc[cc][ni];
            #pragma unroll
            for (int off = 32; off; off >>= 1) v += __shfl_down(v, off, 64);
            if (lane == 0)
                logits[(size_t)(nt * 8 + ni) * NUM_CLASSES + c0 + cc] = v;
        }
}

extern "C" void kernel_launch(void* const* d_in, const int* in_sizes, int n_in,
                              void* d_out, int out_size, void* d_ws, size_t ws_size,
                              hipStream_t stream) {
    const float* f      = (const float*)d_in[0];  // 64x128x14x14
    const float* protos = (const float*)d_in[1];  // 2000x128
    const float* W      = (const float*)d_in[2];  // 200x2000

    float* logits   = (float*)d_out;
    float* min_dist = (float*)d_out + NB * NUM_CLASSES;

    float* xsq = (float*)d_ws;                       // 64*196 f32
    float* psq = xsq + NB * HW;                      // 2048 f32
    float* sim = psq + NP_PAD;                       // 64*2000 f32
    unsigned short* pT = (unsigned short*)(sim + NB * NP);   // 2048*128 bf16
    unsigned short* fT = pT + (size_t)NP_PAD * NF;           // 64*208*128 bf16

    kprep<<<1032, 256, 0, stream>>>(f, protos, xsq, psq, pT, fT);
    kdist<<<dim3(NB, 4), 256, 0, stream>>>(pT, fT, xsq, psq, min_dist, sim);
    klogits<<<dim3(8, 25), 256, 0, stream>>>(sim, W, logits);
}

// Round 6
// 98.466 us; speedup vs baseline: 1.0797x; 1.0797x over previous
//
#include <hip/hip_runtime.h>
#include <hip/hip_bf16.h>

#define NUM_CLASSES 200
#define NF 128
#define NP 2000
#define HW 196
#define MPAD 208        // 13 * 16
#define NB 64
#define EPSV 1e-4f
#define TROW 17         // fp32 staging tile row stride (floats)

typedef __attribute__((ext_vector_type(8))) short short8;   // 8 bf16 = 4 VGPR
typedef __attribute__((ext_vector_type(4))) float f32x4;

static __device__ __forceinline__ unsigned short f2bf(float x) {
    __hip_bfloat16 h = __float2bfloat16(x);
    return __builtin_bit_cast(unsigned short, h);
}

// ---- kernel 1: fully fused distance kernel -----------------------------------
// grid (64 n, 8 p-tiles of 256) [n fastest -> same-n blocks share an XCD L2].
// Per block: A-frags + exact psq from fp32 protos (registers); f[n] transposed
// fp32->bf16 into XOR-swizzled LDS in 13 chunks with inline exact xsq; then
// 13x16 MFMAs/wave, running min, fused relu + sim. No prep kernels, no spill.
__global__ __launch_bounds__(256, 2) void kdist(const float* __restrict__ f,
                                                const float* __restrict__ protos,
                                                float* __restrict__ min_out,
                                                float* __restrict__ sim_out) {
    __shared__ unsigned short sf[MPAD * NF];   // 53,248 B  bf16 B-matrix [hw][k], XOR-swizzled 16B units
    __shared__ float tile[NF * TROW];          //  8,704 B  fp32 staging [k][hw_local]
    __shared__ float sxsq[MPAD];               //    832 B

    const int n    = blockIdx.x;
    const int pt   = blockIdx.y;
    const int t    = threadIdx.x;
    const int wave = t >> 6;
    const int lane = t & 63;
    const int row  = lane & 15;
    const int quad = lane >> 4;
    const int pb   = pt * 256 + wave * 64;

    // ---- A frags from fp32 protos (cvt bf16) + exact fp32 psq ----------------
    short8 A[4][4];
    float psum[4];
    #pragma unroll
    for (int g = 0; g < 4; ++g) {
        int p = pb + g * 16 + row;
        const float* ap = protos + (size_t)(p < NP ? p : NP - 1) * NF + quad * 8;
        psum[g] = 0.f;
        #pragma unroll
        for (int kk = 0; kk < 4; ++kk) {
            float4 v0 = *(const float4*)(ap + kk * 32);
            float4 v1 = *(const float4*)(ap + kk * 32 + 4);
            psum[g] += v0.x * v0.x + v0.y * v0.y + v0.z * v0.z + v0.w * v0.w
                     + v1.x * v1.x + v1.y * v1.y + v1.z * v1.z + v1.w * v1.w;
            short8 a;
            a[0] = (short)f2bf(v0.x); a[1] = (short)f2bf(v0.y);
            a[2] = (short)f2bf(v0.z); a[3] = (short)f2bf(v0.w);
            a[4] = (short)f2bf(v1.x); a[5] = (short)f2bf(v1.y);
            a[6] = (short)f2bf(v1.z); a[7] = (short)f2bf(v1.w);
            A[g][kk] = a;
        }
        // sum over the 4 quads -> every lane holds psq[pb + g*16 + row]
        psum[g] += __shfl_xor(psum[g], 16, 64);
        psum[g] += __shfl_xor(psum[g], 32, 64);
    }

    // ---- stage f[n] -> bf16 [hw][k] in 13 chunks, with inline exact xsq ------
    const int kb   = t >> 2;          // 0..63   (load phase: k row)
    const int hwl  = (t & 3) * 4;     // 0,4,8,12 (load phase: hw within chunk)
    const int hwl2 = t >> 4;          // 0..15   (transpose phase: hw row)
    const int kg   = t & 15;          // 0..15   (transpose phase: 8-k group)

    for (int mt = 0; mt < 13; ++mt) {
        const int hw0 = mt * 16;
        float4 v0 = make_float4(0.f, 0.f, 0.f, 0.f), v1 = v0;
        if (hw0 + hwl + 4 <= HW) {
            v0 = *(const float4*)(f + ((size_t)n * NF + kb) * HW + hw0 + hwl);
            v1 = *(const float4*)(f + ((size_t)n * NF + kb + 64) * HW + hw0 + hwl);
        }
        __syncthreads();   // previous chunk's tile readers are done
        tile[kb * TROW + hwl + 0] = v0.x;
        tile[kb * TROW + hwl + 1] = v0.y;
        tile[kb * TROW + hwl + 2] = v0.z;
        tile[kb * TROW + hwl + 3] = v0.w;
        tile[(kb + 64) * TROW + hwl + 0] = v1.x;
        tile[(kb + 64) * TROW + hwl + 1] = v1.y;
        tile[(kb + 64) * TROW + hwl + 2] = v1.z;
        tile[(kb + 64) * TROW + hwl + 3] = v1.w;
        __syncthreads();
        // transpose-read column hwl2, k = kg*8..+8; cvt; square-sum
        float xp = 0.f;
        unsigned short u[8];
        #pragma unroll
        for (int j = 0; j < 8; ++j) {
            float val = tile[(kg * 8 + j) * TROW + hwl2];
            xp += val * val;
            u[j] = f2bf(val);
        }
        // XOR-swizzled 16B-unit store: unit kg of row (hw0+hwl2) at kg^hwl2
        ((uint4*)sf)[(hw0 + hwl2) * 16 + (kg ^ hwl2)] = *(uint4*)u;
        // xsq: butterfly over the 16 consecutive lanes sharing hwl2
        xp += __shfl_xor(xp, 1, 64);
        xp += __shfl_xor(xp, 2, 64);
        xp += __shfl_xor(xp, 4, 64);
        xp += __shfl_xor(xp, 8, 64);
        if (kg == 0) sxsq[hw0 + hwl2] = (hw0 + hwl2 < HW) ? xp : 3.0e38f;
    }
    __syncthreads();

    // ---- MFMA loop -----------------------------------------------------------
    float runmin[4][4];
    #pragma unroll
    for (int g = 0; g < 4; ++g)
        #pragma unroll
        for (int r = 0; r < 4; ++r) runmin[g][r] = 3.0e38f;

    const short8* sfv = (const short8*)sf;   // 16 units per row
    for (int mt = 0; mt < 13; ++mt) {
        const int base = (mt * 16 + row) * 16;
        short8 b0 = sfv[base + ((quad + 0)  ^ row)];
        short8 b1 = sfv[base + ((quad + 4)  ^ row)];
        short8 b2 = sfv[base + ((quad + 8)  ^ row)];
        short8 b3 = sfv[base + ((quad + 12) ^ row)];
        float xv = sxsq[mt * 16 + row];

        #pragma unroll
        for (int g = 0; g < 4; ++g) {
            f32x4 acc = {0.f, 0.f, 0.f, 0.f};
            acc = __builtin_amdgcn_mfma_f32_16x16x32_bf16(A[g][0], b0, acc, 0, 0, 0);
            acc = __builtin_amdgcn_mfma_f32_16x16x32_bf16(A[g][1], b1, acc, 0, 0, 0);
            acc = __builtin_amdgcn_mfma_f32_16x16x32_bf16(A[g][2], b2, acc, 0, 0, 0);
            acc = __builtin_amdgcn_mfma_f32_16x16x32_bf16(A[g][3], b3, acc, 0, 0, 0);
            #pragma unroll
            for (int r = 0; r < 4; ++r)
                runmin[g][r] = fminf(runmin[g][r], xv - 2.f * acc[r]);
        }
    }

    // ---- min over the 16 D-columns, epilogue ---------------------------------
    #pragma unroll
    for (int g = 0; g < 4; ++g) {
        #pragma unroll
        for (int off = 1; off < 16; off <<= 1)
            #pragma unroll
            for (int r = 0; r < 4; ++r)
                runmin[g][r] = fminf(runmin[g][r], __shfl_xor(runmin[g][r], off, 64));
        #pragma unroll
        for (int r = 0; r < 4; ++r) {
            // psq for p = pb + g*16 + quad*4 + r lives at lane 20*quad + r
            float psq_sel = __shfl(psum[g], 20 * quad + r, 64);
            int p = pb + g * 16 + quad * 4 + r;
            if (row == 0 && p < NP) {
                float m = fmaxf(runmin[g][r] + psq_sel, 0.f);
                min_out[(size_t)n * NP + p] = m;
                sim_out[(size_t)n * NP + p] = logf((m + 1.f) / (m + EPSV));
            }
        }
    }
}

// ---- kernel 2: logits, n-tiled with sim in LDS -------------------------------
// grid (8 n-tiles, 25 c-tiles); block covers 8 n x 8 classes (2 per wave).
__global__ __launch_bounds__(256) void klogits(const float* __restrict__ sim,
                                               const float* __restrict__ W,
                                               float* __restrict__ logits) {
    __shared__ float ssim[8][NP];      // 62.5 KB
    const int nt = blockIdx.x;
    const int cb = blockIdx.y;
    const int t  = threadIdx.x;

    #pragma unroll
    for (int ni = 0; ni < 8; ++ni) {
        const float4* src = (const float4*)(sim + (size_t)(nt * 8 + ni) * NP);
        float4* dst = (float4*)ssim[ni];
        for (int j = t; j < NP / 4; j += 256) dst[j] = src[j];
    }
    __syncthreads();

    const int wave = t >> 6;
    const int lane = t & 63;
    const int c0   = cb * 8 + wave * 2;

    const float4* w0 = (const float4*)(W + (size_t)c0 * NP);
    const float4* w1 = (const float4*)(W + (size_t)(c0 + 1) * NP);

    float acc[2][8];
    #pragma unroll
    for (int cc = 0; cc < 2; ++cc)
        #pragma unroll
        for (int ni = 0; ni < 8; ++ni) acc[cc][ni] = 0.f;

    #pragma unroll
    for (int it = 0; it < 8; ++it) {
        int idx = it * 64 + lane;
        if (idx < NP / 4) {
            float4 a = w0[idx];
            float4 b = w1[idx];
            #pragma unroll
            for (int ni = 0; ni < 8; ++ni) {
                float4 s = ((const float4*)ssim[ni])[idx];
                acc[0][ni] += a.x * s.x + a.y * s.y + a.z * s.z + a.w * s.w;
                acc[1][ni] += b.x * s.x + b.y * s.y + b.z * s.z + b.w * s.w;
            }
        }
    }

    #pragma unroll
    for (int cc = 0; cc < 2; ++cc)
        #pragma unroll
        for (int ni = 0; ni < 8; ++ni) {
            float v = acc[cc][ni];
            #pragma unroll
            for (int off = 32; off; off >>= 1) v += __shfl_down(v, off, 64);
            if (lane == 0)
                logits[(size_t)(nt * 8 + ni) * NUM_CLASSES + c0 + cc] = v;
        }
}

extern "C" void kernel_launch(void* const* d_in, const int* in_sizes, int n_in,
                              void* d_out, int out_size, void* d_ws, size_t ws_size,
                              hipStream_t stream) {
    const float* f      = (const float*)d_in[0];  // 64x128x14x14
    const float* protos = (const float*)d_in[1];  // 2000x128
    const float* W      = (const float*)d_in[2];  // 200x2000

    float* logits   = (float*)d_out;
    float* min_dist = (float*)d_out + NB * NUM_CLASSES;

    float* sim = (float*)d_ws;                    // 64*2000 f32

    kdist<<<dim3(NB, 8), 256, 0, stream>>>(f, protos, min_dist, sim);
    klogits<<<dim3(8, 25), 256, 0, stream>>>(sim, W, logits);
}